// Round 3
// baseline (352.428 us; speedup 1.0000x reference)
//
#include <hip/hip_runtime.h>
#include <hip/hip_bf16.h>

typedef __attribute__((ext_vector_type(8))) __bf16 bf16x8;
typedef __attribute__((ext_vector_type(4))) float f32x4;

constexpr int CI_ = 16, CO_ = 64, H_ = 256, W_ = 256;
constexpr int WTROW = 168;     // padded K (144 -> 168) in bf16 elems; 336B rows
constexpr int RSZ = 258 * 32;  // bytes per kh row-region in xs (258 wp * 32B)

// XOR swizzle: flips addr bits 4..6 with bits 7..9 (bijective, 16B-chunk
// granularity). Read side: kills the stride-128B bank conflict on b128
// B-fragment reads. Write side: makes staging-write bank depend on chunk
// index (lane), capping the fp32->bf16 transpose at 8-way on b32 writes.
__device__ __forceinline__ unsigned swz(unsigned o) {
  return o ^ (((o >> 7) & 7u) << 4);
}

// OIHW fp32 -> wt[co][k], k = tap*16 + ci, padded/zeroed to 168
__global__ void transform_w_kernel(const float* __restrict__ Wg,
                                   unsigned short* __restrict__ wt) {
  int idx = blockIdx.x * 256 + threadIdx.x;  // 64*168 = 10752 exact
  int co = idx / WTROW;
  int kk = idx - co * WTROW;
  float v = 0.f;
  if (kk < 144) {
    int t = kk >> 4;  // tap = kh*3+kw
    int ci = kk & 15;
    v = Wg[(co * 16 + ci) * 9 + t];
  }
  wt[idx] = __builtin_bit_cast(unsigned short, (__bf16)v);
}

// one block per (n,h): reads x (NCHW fp32) directly, computes
// out[n][0..63][h][0..255]. No intermediate global buffer for x.
__global__ __launch_bounds__(256) void conv_fused_kernel(
    const float* __restrict__ x, const unsigned short* __restrict__ wt,
    float* __restrict__ out) {
  __shared__ unsigned char xs[3 * RSZ];        // 24768 B, XOR-swizzled
  __shared__ unsigned short wlds[CO_][WTROW];  // 21504 B

  int tid = threadIdx.x;
  int bid = blockIdx.x;
  // XCD-aware remap: dispatch round-robins bid%8 across XCDs; give each XCD
  // a contiguous (n,h) range so the 3-row halo re-reads hit its own L2.
  int linear = (bid & 7) * 512 + (bid >> 3);  // 4096 = 8*512 exact, bijective
  int h = linear & 255;
  int n = linear >> 8;

  int lane = tid & 63;
  int wave = tid >> 6;

  // stage weights: 21504 B = 1344 uint4
  {
    const uint4* src = (const uint4*)wt;
    uint4* dst = (uint4*)&wlds[0][0];
    for (int c = tid; c < 1344; c += 256) dst[c] = src[c];
  }

  // stage x: fused NCHW fp32 -> bf16 [rr][wp][ci] transpose.
  // 24 wave-units: (rr, ci-pair); each lane loads 2 coalesced float4 (rows
  // ci=2cp and 2cp+1, chunk w=4*lane..4*lane+3), packs ci-pairs to b32.
  {
#pragma unroll
    for (int u = 0; u < 6; ++u) {
      int unit = wave * 6 + u;  // 0..23
      int rr = unit >> 3;       // 0..2
      int cp = unit & 7;        // ci pair: ci = 2cp, 2cp+1
      int hh = h - 1 + rr;
      float4 va = make_float4(0.f, 0.f, 0.f, 0.f);
      float4 vb = va;
      if (hh >= 0 && hh < 256) {
        const float* row =
            x + (((size_t)(n * CI_ + 2 * cp)) * H_ + hh) * W_ + 4 * lane;
        va = *(const float4*)row;
        vb = *(const float4*)(row + H_ * W_);  // next ci plane
      }
      float a4[4] = {va.x, va.y, va.z, va.w};
      float b4[4] = {vb.x, vb.y, vb.z, vb.w};
#pragma unroll
      for (int k = 0; k < 4; ++k) {
        unsigned wp = 4u * lane + 1u + k;
        unsigned pa = __builtin_bit_cast(unsigned short, (__bf16)a4[k]);
        unsigned pb = __builtin_bit_cast(unsigned short, (__bf16)b4[k]);
        *(unsigned*)(xs + rr * RSZ + swz(wp * 32u + 4u * cp)) =
            pa | (pb << 16);
      }
    }
    if (tid < 12) {  // zero pad columns wp=0 and wp=257 (2 chunks each, 3 rr)
      int r = tid >> 2;
      int q = tid & 3;
      unsigned off = ((q >> 1) ? 257u * 32u : 0u) + (q & 1) * 16u;
      *(uint4*)(xs + r * RSZ + swz(off)) = make_uint4(0u, 0u, 0u, 0u);
    }
  }
  __syncthreads();

  int col = lane & 15;  // MFMA column index
  int g = lane >> 4;    // 0..3 k-group

  f32x4 acc[4][4];
#pragma unroll
  for (int i = 0; i < 4; ++i)
#pragma unroll
    for (int j = 0; j < 4; ++j) acc[i][j] = (f32x4){0.f, 0.f, 0.f, 0.f};

  int pxb = wave * 64 + 4 * col;  // lane's base pixel; tile pb = pixel pxb+pb

#pragma unroll
  for (int s = 0; s < 5; ++s) {
    bf16x8 a[4];
#pragma unroll
    for (int cb = 0; cb < 4; ++cb)
      a[cb] = *(const bf16x8*)&wlds[cb * 16 + col][s * 32 + 8 * g];

    int tap = 2 * s + (g >> 1);
    if (tap > 8) tap = 8;   // k>=144: A is zero, B value irrelevant
    int kh = tap / 3;       // xs row-region index (dh+1)
    int kw = tap - kh * 3;  // wp offset
    int ci0 = (g & 1) * 8;

    bf16x8 b[4];
#pragma unroll
    for (int pb = 0; pb < 4; ++pb) {
      unsigned wp = (unsigned)(pxb + pb + kw);
      b[pb] = *(const bf16x8*)(xs + kh * RSZ + swz(wp * 32u + ci0 * 2u));
    }

#pragma unroll
    for (int cb = 0; cb < 4; ++cb)
#pragma unroll
      for (int pb = 0; pb < 4; ++pb)
        acc[cb][pb] = __builtin_amdgcn_mfma_f32_16x16x32_bf16(
            a[cb], b[pb], acc[cb][pb], 0, 0, 0);
  }

  // D layout: col = lane&15, row = g*4 + reg. Lane's pb entries are pixels
  // pxb+0..3 -> contiguous float4 store per (cb, r).
  size_t obase = ((size_t)n * CO_ * H_ + h) * W_ + pxb;
#pragma unroll
  for (int cb = 0; cb < 4; ++cb) {
#pragma unroll
    for (int r = 0; r < 4; ++r) {
      int co = cb * 16 + g * 4 + r;
      f32x4 v = {acc[cb][0][r], acc[cb][1][r], acc[cb][2][r], acc[cb][3][r]};
      *(f32x4*)(out + obase + (size_t)co * (H_ * W_)) = v;
    }
  }
}

extern "C" void kernel_launch(void* const* d_in, const int* in_sizes, int n_in,
                              void* d_out, int out_size, void* d_ws, size_t ws_size,
                              hipStream_t stream) {
  const float* x = (const float*)d_in[0];  // [16,16,256,256]
  const float* W = (const float*)d_in[1];  // [64,16,3,3]
  float* out = (float*)d_out;              // [16,64,256,256]

  unsigned short* wt = (unsigned short*)d_ws;  // 10752 bf16 (21504 B)

  transform_w_kernel<<<42, 256, 0, stream>>>(W, wt);
  conv_fused_kernel<<<4096, 256, 0, stream>>>(x, wt, out);
}